// Round 12
// baseline (359.847 us; speedup 1.0000x reference)
//
#include <hip/hip_runtime.h>
#include <cstdint>
#include <cstddef>

// ---- problem constants ----
#define N_    16
#define C_    16
#define T_    300
#define V_    25
#define D_    400
#define H_    2
#define DH_   200
#define FF_   1600
#define L_    9
#define W_    291
#define NW_   (N_*W_)      // 4656
#define NT_   (N_*T_)      // 4800

#define KP_   416          // K-pad of D for staging (mult of 32); B zero-padded
#define SD_   400          // tight row stride of D-wide intermediates
#define SQKV_ 1200         // tight qkv row stride
#define SFF_  1600         // tight ffc row stride

// fixed workspace head (bytes)
#define WIN_OFF   0u           // w_in_b  [1280][416]
#define WOUT_OFF  1064960u     // w_out_b [512][416]
#define W1_OFF    1490944u     // w1_b    [1792][416]
#define W2_OFF    2981888u     // w2_b    [512][1600]
#define XS_OFF    4620288u     // xs      [4864][400]
#define QKV_OFF   8511488u     // qkv     [4864][1200]
#define Z_OFF     20185088u    // z fp16  [41904][400] (only used when nch>1)
#define HEAD_END  53708288u

// s_waitcnt immediates (gfx9)
#define WAIT_VM3   0xF73
#define WAIT_VM2   0xF72
#define WAIT_VM0   0xF70

using u16 = unsigned short;
using u32 = unsigned int;
using frag  = __attribute__((ext_vector_type(8))) short;   // 8 bf16
using f32x4 = __attribute__((ext_vector_type(4))) float;

__device__ __forceinline__ float bf2f(u16 u){
  return __uint_as_float(((u32)u) << 16);
}
__device__ __forceinline__ u16 f2bf(float f){
  return (u16)((__float_as_uint(f) + 0x8000u) >> 16);   // round-half-up
}
// fp16 for the z buffer (nch>1 fallback path only)
__device__ __forceinline__ u16 f2h(float f){
  _Float16 h = (_Float16)f;
  return *(u16*)&h;
}
__device__ __forceinline__ float h2f(u16 u){
  _Float16 h = *(_Float16*)&u;
  return (float)h;
}
// gelu: sigmoid form, v * sigmoid(1.702 v). Max dev from exact erf-gelu ~0.02;
// invisible after FFN2 sum @ bf16.
__device__ __forceinline__ float gelu_f(float v){
  float s = __expf(-1.702f * v);
  return v * __builtin_amdgcn_rcpf(1.f + s);
}
__device__ __forceinline__ void unpack8(uint4 v, float* o){
  o[0] = bf2f((u16)(v.x & 0xffffu)); o[1] = bf2f((u16)(v.x >> 16));
  o[2] = bf2f((u16)(v.y & 0xffffu)); o[3] = bf2f((u16)(v.y >> 16));
  o[4] = bf2f((u16)(v.z & 0xffffu)); o[5] = bf2f((u16)(v.z >> 16));
  o[6] = bf2f((u16)(v.w & 0xffffu)); o[7] = bf2f((u16)(v.w >> 16));
}

__device__ __forceinline__ void convw_body(const float* src, u16* dst,
                                           int dN, int dK, int sN, int sK, int idx){
  if (idx >= dN * dK) return;
  int n = idx / dK, k = idx % dK;
  dst[idx] = (n < sN && k < sK) ? f2bf(src[(size_t)n * sK + k]) : (u16)0;
}

// ---- mega-prep: embed (LDS-transposed, coalesced) | 4x weight conversions ----
// ranges: [0,4800) embed (block per (n,t)), [4800,6880) w_in, [6880,7712) w_out,
// [7712,10624) w1(1792 rows), [10624,13824) w2
#define PREP_GRID 13824
__global__ __launch_bounds__(256) void prep_kernel(const float* __restrict__ x,
                                                   const float* __restrict__ pe,
                                                   const float* __restrict__ w_in,
                                                   const float* __restrict__ w_out,
                                                   const float* __restrict__ w1,
                                                   const float* __restrict__ w2,
                                                   u16* __restrict__ xs,
                                                   u16* __restrict__ w_in_b,
                                                   u16* __restrict__ w_out_b,
                                                   u16* __restrict__ w1_b,
                                                   u16* __restrict__ w2_b){
  __shared__ float xv[400];
  int b = blockIdx.x;
  int tid = threadIdx.x;
  if (b < 4800){
    // block = (n,t): read x[n,:,t,:] in (c,v) order (25-float coalesced runs),
    // write xs row in d order (coalesced). d = v*16 + c.
    int t = b % T_, n = b / T_;
    for (int i = tid; i < 400; i += 256){
      int c = i / 25, v = i - c*25;
      xv[i] = x[(((size_t)(n*C_ + c))*T_ + t)*V_ + v];
    }
    __syncthreads();
    for (int d = tid; d < 400; d += 256){
      float val = xv[(d & 15)*25 + (d >> 4)] + pe[t*D_ + d];
      xs[(size_t)b * D_ + d] = f2bf(val);
    }
  } else if (b < 6880){
    convw_body(w_in,  w_in_b,  1280, KP_, 1200, D_,  (b - 4800) * 256 + tid);
  } else if (b < 7712){
    convw_body(w_out, w_out_b,  512, KP_,  400, D_,  (b - 6880) * 256 + tid);
  } else if (b < 10624){
    convw_body(w1,    w1_b,   1792, KP_, 1600, D_,  (b - 7712) * 256 + tid);
  } else {
    convw_body(w2,    w2_b,    512, SFF_, 400, FF_, (b - 10624) * 256 + tid);
  }
}

// ---- MFMA GEMM: 128x256 block tile, 8 waves (2M x 4N) of 64x64 each,
//      16 MFMA per wave-iter from 4+4 fragment reads (32.8 FLOP/LDS-byte),
//      3-deep LDS pipeline, cooperative global_load_lds (3 loads/thread:
//      1 A + 2 B halves), raw s_barrier + counted vmcnt(3) (never 0 mid-loop).
//      T5: setprio(1) around the MFMA cluster (role-diverse waves). ----
template<int ACT>
__global__ __launch_bounds__(512) void gemm_mfma(const u16* __restrict__ A, int lda,
                                                 const u16* __restrict__ B, int ldb,
                                                 const float* __restrict__ bias,
                                                 u16* __restrict__ C, int ldc,
                                                 int Nn, int KPd,
                                                 int gx, int gy){
  __shared__ u16 smem[36864];              // 72KB: A 3x8KB [0,12288), B 3x16KB [12288,36864)
  int id = blockIdx.x;
  int c  = id & 7, t = id >> 3;
  int bx = t % gx;
  int by = (t / gx) * 8 + c;               // XCD c owns M-tile residue class
  if (by >= gy) return;
  const int m0 = by * 128, n0 = bx * 256;

  const int tid  = threadIdx.x;
  const int lane = tid & 63;
  const int wv   = tid >> 6;               // 0..7
  const int quad = lane >> 4, l16 = lane & 15;
  const int wm   = wv & 1,   wn  = wv >> 1;   // wave grid: 2M x 4N, out 64x64/wave

  // staging map: A tile 128x32 (1 load/thread), B tile 256x32 (2 loads/thread)
  const int srow = tid >> 2;                          // 0..127
  const int sseg = (tid & 3) ^ ((tid >> 3) & 3);      // xor-swizzled k-segment
  const u16* Ag = A + (size_t)(m0 + srow) * lda + sseg*8;
  const u16* Bg = B + (size_t)(n0 + srow) * ldb + sseg*8;

  f32x4 acc[4][4] = {};
  const int sa = quad ^ ((l16 >> 1) & 3);             // read-side slot

  auto stage = [&](int buf, int kt){
    __builtin_amdgcn_global_load_lds(
        (const __attribute__((address_space(1))) void*)(Ag + kt),
        (__attribute__((address_space(3))) void*)(&smem[buf*4096 + wv*512]), 16, 0, 0);
    __builtin_amdgcn_global_load_lds(
        (const __attribute__((address_space(1))) void*)(Bg + kt),
        (__attribute__((address_space(3))) void*)(&smem[12288 + buf*8192 + wv*512]), 16, 0, 0);
    __builtin_amdgcn_global_load_lds(
        (const __attribute__((address_space(1))) void*)(Bg + kt + (size_t)128*ldb),
        (__attribute__((address_space(3))) void*)(&smem[12288 + buf*8192 + 4096 + wv*512]), 16, 0, 0);
  };

  const int nit = KPd >> 5;                // 13 or 50
  stage(0, 0);
  stage(1, 32);
  int nb = 2;
  for (int it = 0; it < nit; ++it){
    if (it < nit - 1) __builtin_amdgcn_s_waitcnt(WAIT_VM3);
    else              __builtin_amdgcn_s_waitcnt(WAIT_VM0);
    __builtin_amdgcn_s_barrier();
    if (it + 2 < nit){
      stage(nb, (it + 2) << 5);
      nb = (nb == 2) ? 0 : nb + 1;
    }
    const int buf = it % 3;
    const u16* Ar = &smem[buf*4096];
    const u16* Br = &smem[12288 + buf*8192];
    frag af[4], bfr[4];
    #pragma unroll
    for (int i = 0; i < 4; ++i)
      af[i]  = *(const frag*)(&Ar[(wm*64 + i*16 + l16)*32 + sa*8]);
    #pragma unroll
    for (int j = 0; j < 4; ++j)
      bfr[j] = *(const frag*)(&Br[(wn*64 + j*16 + l16)*32 + sa*8]);
    __builtin_amdgcn_s_setprio(1);
    #pragma unroll
    for (int i = 0; i < 4; ++i)
      #pragma unroll
      for (int j = 0; j < 4; ++j)
        acc[i][j] = __builtin_amdgcn_mfma_f32_16x16x32_bf16(af[i], bfr[j], acc[i][j], 0, 0, 0);
    __builtin_amdgcn_s_setprio(0);
  }

  __builtin_amdgcn_s_barrier();            // staging LDS now reusable

  u16* ep = &smem[wv * 4608];              // per-wave 64 rows x 72 u16 (8x4608=36864)
  #pragma unroll
  for (int j = 0; j < 4; ++j){
    int n = n0 + wn*64 + j*16 + l16;
    float bj = (n < Nn) ? bias[n] : 0.f;
    #pragma unroll
    for (int i = 0; i < 4; ++i){
      #pragma unroll
      for (int r = 0; r < 4; ++r){
        float v = acc[i][j][r] + bj;
        if (ACT) v = gelu_f(v);
        ep[(i*16 + quad*4 + r)*72 + j*16 + l16] = f2bf(v);
      }
    }
  }
  #pragma unroll
  for (int p = 0; p < 8; ++p){
    int row = p*8 + (lane >> 3);
    int seg = lane & 7;
    int nc  = n0 + wn*64 + seg*8;
    if (nc < Nn){                           // Nn multiple of 8 -> seg-exact
      uint4 v = *(const uint4*)(&ep[row*72 + seg*8]);
      *(uint4*)(C + (size_t)(m0 + wm*64 + row)*ldc + nc) = v;
    }
  }
}

// ---- MFMA GEMM, 128x128 variant (R2-verified): 8 waves (2M x 4N) of 64x32,
//      48KB LDS -> 3 blocks/CU. Used for the small-M qkv GEMM (fill-bound)
//      and as the FF1 column-remainder (cols 1536..1599, ACT=1). ----
template<int ACT>
__global__ __launch_bounds__(512) void gemm_mfma128(const u16* __restrict__ A, int lda,
                                                    const u16* __restrict__ B, int ldb,
                                                    const float* __restrict__ bias,
                                                    u16* __restrict__ C, int ldc,
                                                    int Nn, int KPd,
                                                    int gx, int gy){
  __shared__ u16 smem[24576];              // 48KB: A bufs [0,12288), B bufs [12288,24576)
  int id = blockIdx.x;
  int c  = id & 7, t = id >> 3;
  int bx = t % gx;
  int by = (t / gx) * 8 + c;               // XCD c owns M-tile residue class
  if (by >= gy) return;
  const int m0 = by * 128, n0 = bx * 128;

  const int tid  = threadIdx.x;
  const int lane = tid & 63;
  const int wv   = tid >> 6;               // 0..7
  const int quad = lane >> 4, l16 = lane & 15;
  const int wm   = wv & 1,   wn  = wv >> 1;   // wave grid: 2M x 4N, out 64x32/wave

  // staging map: 512 threads cover a full 128x32 tile (1 load each per operand)
  const int srow = tid >> 2;                          // 0..127
  const int sseg = (tid & 3) ^ ((tid >> 3) & 3);      // xor-swizzled k-segment
  const u16* Ag = A + (size_t)(m0 + srow) * lda + sseg*8;
  const u16* Bg = B + (size_t)(n0 + srow) * ldb + sseg*8;

  f32x4 acc[4][2] = {};
  const int sa = quad ^ ((l16 >> 1) & 3);             // read-side slot

  auto stage = [&](int buf, int kt){
    __builtin_amdgcn_global_load_lds(
        (const __attribute__((address_space(1))) void*)(Ag + kt),
        (__attribute__((address_space(3))) void*)(&smem[buf*4096 + wv*512]), 16, 0, 0);
    __builtin_amdgcn_global_load_lds(
        (const __attribute__((address_space(1))) void*)(Bg + kt),
        (__attribute__((address_space(3))) void*)(&smem[12288 + buf*4096 + wv*512]), 16, 0, 0);
  };

  const int nit = KPd >> 5;                // 13
  stage(0, 0);
  stage(1, 32);
  int nb = 2;
  for (int it = 0; it < nit; ++it){
    if (it < nit - 1) __builtin_amdgcn_s_waitcnt(WAIT_VM2);
    else              __builtin_amdgcn_s_waitcnt(WAIT_VM0);
    __builtin_amdgcn_s_barrier();
    if (it + 2 < nit){
      stage(nb, (it + 2) << 5);
      nb = (nb == 2) ? 0 : nb + 1;
    }
    const int buf = it % 3;
    const u16* Ar = &smem[buf*4096];
    const u16* Br = &smem[12288 + buf*4096];
    frag af[4], bfr[2];
    #pragma unroll
    for (int i = 0; i < 4; ++i)
      af[i]  = *(const frag*)(&Ar[(wm*64 + i*16 + l16)*32 + sa*8]);
    #pragma unroll
    for (int j = 0; j < 2; ++j)
      bfr[j] = *(const frag*)(&Br[(wn*32 + j*16 + l16)*32 + sa*8]);
    __builtin_amdgcn_s_setprio(1);
    #pragma unroll
    for (int i = 0; i < 4; ++i)
      #pragma unroll
      for (int j = 0; j < 2; ++j)
        acc[i][j] = __builtin_amdgcn_mfma_f32_16x16x32_bf16(af[i], bfr[j], acc[i][j], 0, 0, 0);
    __builtin_amdgcn_s_setprio(0);
  }

  __builtin_amdgcn_s_barrier();            // staging LDS now reusable

  u16* ep = &smem[wv * 2560];              // per-wave 64 rows x 40 u16
  #pragma unroll
  for (int j = 0; j < 2; ++j){
    int n = n0 + wn*32 + j*16 + l16;
    float bj = (n < Nn) ? bias[n] : 0.f;
    #pragma unroll
    for (int i = 0; i < 4; ++i){
      #pragma unroll
      for (int r = 0; r < 4; ++r){
        float v = acc[i][j][r] + bj;
        if (ACT) v = gelu_f(v);
        ep[(i*16 + quad*4 + r)*40 + j*16 + l16] = f2bf(v);
      }
    }
  }
  #pragma unroll
  for (int p = 0; p < 4; ++p){
    int row = p*16 + (lane >> 2);
    int seg = lane & 3;
    int nc  = n0 + wn*32 + seg*8;
    if (nc < Nn){                           // Nn multiple of 8 -> seg-exact
      uint4 v = *(const uint4*)(&ep[row*40 + seg*8]);
      *(uint4*)(C + (size_t)(m0 + wm*64 + row)*ldc + nc) = v;
    }
  }
}

// ---- window-batched attention: 8 windows/block, bf16 LDS slab staging ----
#define WB_     8
#define ATT_NB  37                   // ceil(291/8)
#define ATT_GRID (N_ * ATT_NB)       // 592
__global__ __launch_bounds__(256) void attn_kernel(const u16* __restrict__ qkv,
                                                   u16* __restrict__ o,
                                                   int g0, int gend){
  __shared__ u16 kv[20480];          // 16 rows x 1200 u16 bf16
  __shared__ float att[WB_ * 2 * 81];  // [w][h][qi][ki]
  const int b  = blockIdx.x;
  const int n  = b / ATT_NB;
  const int w0 = (b - n * ATT_NB) * WB_;
  const int gbase = n * W_ + w0;
  if (gbase >= gend || gbase + WB_ <= g0) return;   // block outside chunk

  const int tid  = threadIdx.x;
  const int lane = tid & 63;
  const int wv   = tid >> 6;

  // stage 16 rows (38400B, rounded to 10 x 4KB rounds; over-read in-bounds
  // of the padded qkv buffer [4864][1200])
  const char* gsrc = (const char*)(qkv + (size_t)(n * T_ + w0) * SQKV_);
  #pragma unroll
  for (int j = 0; j < 10; ++j){
    __builtin_amdgcn_global_load_lds(
        (const __attribute__((address_space(1))) void*)(gsrc + j*4096 + wv*1024 + lane*16),
        (__attribute__((address_space(3))) void*)((char*)kv + j*4096 + wv*1024),
        16, 0, 0);
  }
  __builtin_amdgcn_s_waitcnt(WAIT_VM0);
  __syncthreads();

  // scores: 1296 tasks, each a 200-wide bf16 dot via 16B LDS reads
  for (int i = tid; i < WB_ * 162; i += 256){
    int w  = i / 162;
    int r  = i - w * 162;
    int h  = r / 81;
    int p  = r - h * 81;
    int qi = p / 9, ki = p - qi * 9;
    const u16* qp = kv + (w + qi) * 1200 + h * DH_;
    const u16* kp = kv + (w + ki) * 1200 + D_ + h * DH_;
    float s = 0.f;
    #pragma unroll 5
    for (int cch = 0; cch < 25; ++cch){
      float qa[8], kb[8];
      unpack8(*(const uint4*)(qp + cch*8), qa);
      unpack8(*(const uint4*)(kp + cch*8), kb);
      #pragma unroll
      for (int e = 0; e < 8; ++e) s += qa[e] * kb[e];
    }
    att[i] = s * 0.07071067811865475f;   // 1/sqrt(200)
  }
  __syncthreads();

  // softmax in place: one thread per (w,h,qi) row of 9
  if (tid < WB_ * 18){
    float* row = att + tid * 9;
    float mx = row[0];
    #pragma unroll
    for (int j = 1; j < 9; ++j) mx = fmaxf(mx, row[j]);
    float e[9]; float sum = 0.f;
    #pragma unroll
    for (int j = 0; j < 9; ++j){ e[j] = __expf(row[j] - mx); sum += e[j]; }
    float inv = 1.f / sum;
    #pragma unroll
    for (int j = 0; j < 9; ++j) row[j] = e[j] * inv;
  }
  __syncthreads();

  // PV: 7200 tasks, each 4 consecutive d (8B v reads), 9 MACs each
  for (int i = tid; i < WB_ * 900; i += 256){
    int w  = i / 900;
    int r  = i - w * 900;
    int l  = r / 100;
    int c4 = r - l * 100;                  // d0 = c4*4
    int h  = (c4 >= 50) ? 1 : 0;
    const float* ap = att + (w*2 + h)*81 + l*9;
    float o4[4] = {0.f, 0.f, 0.f, 0.f};
    #pragma unroll
    for (int ki = 0; ki < 9; ++ki){
      float a = ap[ki];
      uint2 vv = *(const uint2*)(kv + (w + ki)*1200 + 2*D_ + c4*4);
      o4[0] += a * bf2f((u16)(vv.x & 0xffffu));
      o4[1] += a * bf2f((u16)(vv.x >> 16));
      o4[2] += a * bf2f((u16)(vv.y & 0xffffu));
      o4[3] += a * bf2f((u16)(vv.y >> 16));
    }
    int g = gbase + w;
    if (w0 + w < W_ && g >= g0 && g < gend){
      u32 lo = (u32)f2bf(o4[0]) | ((u32)f2bf(o4[1]) << 16);
      u32 hi = (u32)f2bf(o4[2]) | ((u32)f2bf(o4[3]) << 16);
      *(uint2*)(o + ((size_t)(g - g0) * L_ + l) * SD_ + c4*4) = make_uint2(lo, hi);
    }
  }
}

// ---- LN1: h = LN(xs_window + y), wave-per-row ----
__global__ __launch_bounds__(256) void ln1_kernel(const u16* __restrict__ y,
                                                  const float* __restrict__ gam,
                                                  const float* __restrict__ bet,
                                                  u16* __restrict__ out,
                                                  const u16* __restrict__ xs,
                                                  int g0){
  const int wv = threadIdx.x >> 6, lane = threadIdx.x & 63;
  const int r = blockIdx.x * 4 + wv;
  const int g = g0 + r / L_, l = r % L_;
  const int n = g / W_, w = g % W_;
  const u16* arow = xs + ((size_t)(n*T_ + w + l)) * SD_;
  const u16* brow = y + (size_t)r * SD_;

  const bool act = lane < 50;
  float v[8];
  float s = 0.f, s2 = 0.f;
  if (act){
    float a8[8], b8[8];
    unpack8(*(const uint4*)(arow + lane*8), a8);
    unpack8(*(const uint4*)(brow + lane*8), b8);
    #pragma unroll
    for (int i = 0; i < 8; ++i){ v[i] = a8[i] + b8[i]; s += v[i]; s2 += v[i]*v[i]; }
  } else {
    #pragma unroll
    for (int i = 0; i < 8; ++i) v[i] = 0.f;
  }
  #pragma unroll
  for (int off = 32; off; off >>= 1){
    s  += __shfl_xor(s,  off);
    s2 += __shfl_xor(s2, off);
  }
  float mean = s * (1.f / D_);
  float rstd = rsqrtf(s2 * (1.f / D_) - mean*mean + 1e-5f);
  if (act){
    float4 ga = *(const float4*)(gam + lane*8);
    float4 gb = *(const float4*)(gam + lane*8 + 4);
    float4 ba = *(const float4*)(bet + lane*8);
    float4 bb = *(const float4*)(bet + lane*8 + 4);
    float gg[8] = {ga.x,ga.y,ga.z,ga.w, gb.x,gb.y,gb.z,gb.w};
    float bb8[8]= {ba.x,ba.y,ba.z,ba.w, bb.x,bb.y,bb.z,bb.w};
    u32 o4[4];
    #pragma unroll
    for (int i = 0; i < 4; ++i){
      u16 lo = f2bf((v[2*i]   - mean) * rstd * gg[2*i]   + bb8[2*i]);
      u16 hi = f2bf((v[2*i+1] - mean) * rstd * gg[2*i+1] + bb8[2*i+1]);
      o4[i] = (u32)lo | ((u32)hi << 16);
    }
    *(uint4*)(out + (size_t)r * SD_ + lane*8) = make_uint4(o4[0],o4[1],o4[2],o4[3]);
  }
}

// ---- fused LN2 + gather + transpose (nch==1 path; z eliminated) ----
// Each window-row (w,l) feeds exactly ONE output row t=(w>>1)+l, so the
// scatter has fan-out 1: one block per (n,t) loads its <=18 contributor
// (h,y) row-pairs (each consumed exactly once grid-wide), runs wave-per-row
// LN2 in-register, accumulates fp32 partials, writes transposed output.
// Blocks with t>153 have no contributors -> write zeros (matches reference).
__global__ __launch_bounds__(256) void ln2_gather(const u16* __restrict__ h,
                                                  const u16* __restrict__ y,
                                                  const float* __restrict__ gam,
                                                  const float* __restrict__ bet,
                                                  float* __restrict__ dout){
  __shared__ float buf[4][400];
  const int b = blockIdx.x;               // 0..4799
  const int t = b % T_;
  const int n = b / T_;
  const int wv = threadIdx.x >> 6, lane = threadIdx.x & 63;
  const bool act = lane < 50;

  float gg[8], bb8[8];
  if (act){
    float4 ga = *(const float4*)(gam + lane*8);
    float4 gb = *(const float4*)(gam + lane*8 + 4);
    float4 ba = *(const float4*)(bet + lane*8);
    float4 bb = *(const float4*)(bet + lane*8 + 4);
    gg[0]=ga.x; gg[1]=ga.y; gg[2]=ga.z; gg[3]=ga.w;
    gg[4]=gb.x; gg[5]=gb.y; gg[6]=gb.z; gg[7]=gb.w;
    bb8[0]=ba.x; bb8[1]=ba.y; bb8[2]=ba.z; bb8[3]=ba.w;
    bb8[4]=bb.x; bb8[5]=bb.y; bb8[6]=bb.z; bb8[7]=bb.w;
  }
  float racc[8] = {0.f,0.f,0.f,0.f,0.f,0.f,0.f,0.f};

  // contributor slots: idx -> (l = idx>>1, parity = idx&1), w = 2*(t-l)+parity
  for (int idx = wv; idx < 18; idx += 4){   // wave-uniform control flow
    int l  = idx >> 1;
    int dt = t - l;
    if (dt < 0 || dt > 145) continue;
    int w = dt * 2 + (idx & 1);
    if (w >= W_) continue;
    size_t r = ((size_t)(n * W_ + w)) * L_ + l;
    const u16* arow = h + r * SD_;
    const u16* brow = y + r * SD_;
    float v[8];
    float s = 0.f, s2 = 0.f;
    if (act){
      float a8[8], b8[8];
      unpack8(*(const uint4*)(arow + lane*8), a8);
      unpack8(*(const uint4*)(brow + lane*8), b8);
      #pragma unroll
      for (int i = 0; i < 8; ++i){ v[i] = a8[i] + b8[i]; s += v[i]; s2 += v[i]*v[i]; }
    } else {
      #pragma unroll
      for (int i = 0; i < 8; ++i) v[i] = 0.f;
    }
    #pragma unroll
    for (int off = 32; off; off >>= 1){
      s  += __shfl_xor(s,  off);
      s2 += __shfl_xor(s2, off);
    }
    float mean = s * (1.f / D_);
    float rstd = rsqrtf(s2 * (1.f / D_) - mean*mean + 1e-5f);
    if (act){
      #pragma unroll
      for (int i = 0; i < 8; ++i)
        racc[i] += (v[i] - mean) * rstd * gg[i] + bb8[i];
    }
  }
  if (act){
    #pragma unroll
    for (int i = 0; i < 8; ++i) buf[wv][lane*8 + i] = racc[i];
  }
  __syncthreads();
  for (int d = threadIdx.x; d < D_; d += 256){
    float s = buf[0][d] + buf[1][d] + buf[2][d] + buf[3][d];
    dout[(((size_t)(n*C_ + (d & 15)))*T_ + t)*V_ + (d >> 4)] = s;
  }
}

// ---- LN2 -> dense z rows in fp16 (nch>1 fallback path) ----
__global__ __launch_bounds__(256) void ln2z_kernel(const u16* __restrict__ h,
                                                   const u16* __restrict__ y,
                                                   const float* __restrict__ gam,
                                                   const float* __restrict__ bet,
                                                   u16* __restrict__ z,
                                                   int g0){
  const int wv = threadIdx.x >> 6, lane = threadIdx.x & 63;
  const int r = blockIdx.x * 4 + wv;
  const u16* arow = h + (size_t)r * SD_;
  const u16* brow = y + (size_t)r * SD_;

  const bool act = lane < 50;
  float v[8];
  float s = 0.f, s2 = 0.f;
  if (act){
    float a8[8], b8[8];
    unpack8(*(const uint4*)(arow + lane*8), a8);
    unpack8(*(const uint4*)(brow + lane*8), b8);
    #pragma unroll
    for (int i = 0; i < 8; ++i){ v[i] = a8[i] + b8[i]; s += v[i]; s2 += v[i]*v[i]; }
  } else {
    #pragma unroll
    for (int i = 0; i < 8; ++i) v[i] = 0.f;
  }
  #pragma unroll
  for (int off = 32; off; off >>= 1){
    s  += __shfl_xor(s,  off);
    s2 += __shfl_xor(s2, off);
  }
  float mean = s * (1.f / D_);
  float rstd = rsqrtf(s2 * (1.f / D_) - mean*mean + 1e-5f);
  if (act){
    float4 ga = *(const float4*)(gam + lane*8);
    float4 gb = *(const float4*)(gam + lane*8 + 4);
    float4 ba = *(const float4*)(bet + lane*8);
    float4 bb = *(const float4*)(bet + lane*8 + 4);
    float gg[8] = {ga.x,ga.y,ga.z,ga.w, gb.x,gb.y,gb.z,gb.w};
    float bb8[8]= {ba.x,ba.y,ba.z,ba.w, bb.x,bb.y,bb.z,bb.w};
    u32 o4[4];
    #pragma unroll
    for (int i = 0; i < 4; ++i){
      u16 lo = f2h((v[2*i]   - mean) * rstd * gg[2*i]   + bb8[2*i]);
      u16 hi = f2h((v[2*i+1] - mean) * rstd * gg[2*i+1] + bb8[2*i+1]);
      o4[i] = (u32)lo | ((u32)hi << 16);
    }
    *(uint4*)(z + ((size_t)(g0 * L_) + r) * SD_ + lane*8) = make_uint4(o4[0],o4[1],o4[2],o4[3]);
  }
}

// ---- gather + transpose from z (nch>1 fallback path) ----
__global__ __launch_bounds__(256) void gather_final(const u16* __restrict__ z,
                                                    float* __restrict__ dout){
  int idx = blockIdx.x * 256 + threadIdx.x;
  if (idx >= NT_ * D_) return;
  int d  = idx % D_;
  int nt = idx / D_;
  int t  = nt % T_;
  int n  = nt / T_;
  float s = 0.f;
  #pragma unroll
  for (int l = 0; l < L_; ++l){
    int dt = t - l;
    if (dt >= 0 && dt <= 145){            // w = 2*dt in [0, 291)
      int w = dt * 2;
      const u16* zp = z + ((size_t)((n*W_ + w)*L_ + l)) * SD_ + d;
      s += h2f(zp[0]);
      if (w + 1 < W_) s += h2f(zp[(size_t)L_ * SD_]);   // row (w+1, l)
    }
  }
  dout[(((size_t)(n*C_ + (d & 15)))*T_ + t)*V_ + (d >> 4)] = s;
}

extern "C" void kernel_launch(void* const* d_in, const int* in_sizes, int n_in,
                              void* d_out, int out_size, void* d_ws, size_t ws_size,
                              hipStream_t stream){
  (void)in_sizes; (void)n_in; (void)out_size;
  const float* x     = (const float*)d_in[0];
  const float* pe    = (const float*)d_in[1];
  const float* w_in  = (const float*)d_in[2];
  const float* b_in  = (const float*)d_in[3];
  const float* w_out = (const float*)d_in[4];
  const float* b_out = (const float*)d_in[5];
  const float* w1    = (const float*)d_in[6];
  const float* b1    = (const float*)d_in[7];
  const float* w2    = (const float*)d_in[8];
  const float* b2    = (const float*)d_in[9];
  const float* ln1g  = (const float*)d_in[10];
  const float* ln1b  = (const float*)d_in[11];
  const float* ln2g  = (const float*)d_in[12];
  const float* ln2b  = (const float*)d_in[13];

  // ws_size-adaptive chunk count (deterministic -> graph-safe).
  // Per-chunk footprint: y_c + h_c + ffc = RCP*4800 B (o_c aliases ffc head:
  // o_c is dead once FF1 writes ffc, and ffc is dead before the next chunk's
  // attn writes o_c).
  int nch = 3;
  {
    size_t need1 = (size_t)HEAD_END + (size_t)41984 * 4800;   // 1 chunk
    size_t need2 = (size_t)HEAD_END + (size_t)20992 * 4800;   // 2 chunks
    if (ws_size >= need1 + (1u<<20)) nch = 1;
    else if (ws_size >= need2 + (1u<<20)) nch = 2;
  }
  const int CW  = NW_ / nch;
  const int RC  = CW * L_;
  const int RCP = ((RC + 127) / 128) * 128;

  char* ws = (char*)d_ws;
  u16*   w_in_b  = (u16*)(ws + WIN_OFF);
  u16*   w_out_b = (u16*)(ws + WOUT_OFF);
  u16*   w1_b    = (u16*)(ws + W1_OFF);
  u16*   w2_b    = (u16*)(ws + W2_OFF);
  u16*   xs      = (u16*)(ws + XS_OFF);
  u16*   qkv     = (u16*)(ws + QKV_OFF);
  u16*   z       = (u16*)(ws + Z_OFF);
  u16*   y_c     = (u16*)(ws + HEAD_END);
  u16*   h_c     = y_c + (size_t)RCP * SD_;
  u16*   ffc     = h_c + (size_t)RCP * SD_;
  u16*   o_c     = ffc;                      // aliased (see lifetime note above)

  // one launch: embed + all 4 weight conversions
  prep_kernel<<<PREP_GRID, 256, 0, stream>>>(x, pe, w_in, w_out, w1, w2,
                                             xs, w_in_b, w_out_b, w1_b, w2_b);

  // qkv = xs @ w_in^T + b_in   [4800 x 1200] -- 128x128 variant (fill-bound)
  {
    int gx = 10, gy = (NT_ + 127)/128, gy8 = (gy + 7) & ~7;
    gemm_mfma128<0><<<gx*gy8, 512, 0, stream>>>(
        xs, SD_, w_in_b, KP_, b_in, qkv, SQKV_, 1200, KP_, gx, gy);
  }

  const int gyc = RCP/128, gyc8 = (gyc + 7) & ~7;

  for (int g0 = 0; g0 < NW_; g0 += CW){
    attn_kernel<<<ATT_GRID, 256, 0, stream>>>(qkv, o_c, g0, g0 + CW);

    gemm_mfma<0><<<2*gyc8, 512, 0, stream>>>(
        o_c, SD_, w_out_b, KP_, b_out, y_c, SD_, D_, KP_, 2, gyc);

    ln1_kernel<<<RC/4, 256, 0, stream>>>(y_c, ln1g, ln1b, h_c, xs, g0);

    // FF1 main: cols 0..1535 (gx=6, no zero-pad column block)
    gemm_mfma<1><<<6*gyc8, 512, 0, stream>>>(
        h_c, SD_, w1_b, KP_, b1, ffc, SFF_, 1536, KP_, 6, gyc);
    // FF1 remainder: cols 1536..1599 (128-wide tile, 64 real cols)
    gemm_mfma128<1><<<gyc8, 512, 0, stream>>>(
        h_c, SD_, w1_b + (size_t)1536*KP_, KP_, b1 + 1536,
        ffc + 1536, SFF_, 64, KP_, 1, gyc);

    gemm_mfma<0><<<2*gyc8, 512, 0, stream>>>(
        ffc, SFF_, w2_b, SFF_, b2, y_c, SD_, D_, SFF_, 2, gyc);

    if (nch > 1)
      ln2z_kernel<<<RC/4, 256, 0, stream>>>(h_c, y_c, ln2g, ln2b, z, g0);
  }

  if (nch == 1)
    ln2_gather<<<NT_, 256, 0, stream>>>(h_c, y_c, ln2g, ln2b, (float*)d_out);
  else
    gather_final<<<(NT_*D_ + 255)/256, 256, 0, stream>>>(z, (float*)d_out);
}

// Round 13
// 351.760 us; speedup vs baseline: 1.0230x; 1.0230x over previous
//
#include <hip/hip_runtime.h>
#include <cstdint>
#include <cstddef>

// ---- problem constants ----
#define N_    16
#define C_    16
#define T_    300
#define V_    25
#define D_    400
#define H_    2
#define DH_   200
#define FF_   1600
#define L_    9
#define W_    291
#define NW_   (N_*W_)      // 4656
#define NT_   (N_*T_)      // 4800

#define KP_   416          // K-pad of D for staging (mult of 32); B zero-padded
#define SD_   400          // tight row stride of D-wide intermediates
#define SQKV_ 1200         // tight qkv row stride
#define SFF_  1600         // tight ffc row stride

// fixed workspace head (bytes)
#define WIN_OFF   0u           // w_in_b  [1280][416]
#define WOUT_OFF  1064960u     // w_out_b [512][416]
#define W1_OFF    1490944u     // w1_b    [1792][416]
#define W2_OFF    2981888u     // w2_b    [512][1600]
#define XS_OFF    4620288u     // xs      [4864][400]
#define QKV_OFF   8511488u     // qkv     [4864][1200]
#define Z_OFF     20185088u    // z fp16  [41904][400] (only used when nch>1)
#define HEAD_END  53708288u

// s_waitcnt immediates (gfx9)
#define WAIT_VM3   0xF73
#define WAIT_VM2   0xF72
#define WAIT_VM0   0xF70

using u16 = unsigned short;
using u32 = unsigned int;
using frag  = __attribute__((ext_vector_type(8))) short;   // 8 bf16
using f32x4 = __attribute__((ext_vector_type(4))) float;

__device__ __forceinline__ float bf2f(u16 u){
  return __uint_as_float(((u32)u) << 16);
}
__device__ __forceinline__ u16 f2bf(float f){
  return (u16)((__float_as_uint(f) + 0x8000u) >> 16);   // round-half-up
}
// fp16 for the z buffer (nch>1 fallback path only)
__device__ __forceinline__ u16 f2h(float f){
  _Float16 h = (_Float16)f;
  return *(u16*)&h;
}
__device__ __forceinline__ float h2f(u16 u){
  _Float16 h = *(_Float16*)&u;
  return (float)h;
}
// gelu: sigmoid form, v * sigmoid(1.702 v). Max dev from exact erf-gelu ~0.02;
// invisible after FFN2 sum @ bf16.
__device__ __forceinline__ float gelu_f(float v){
  float s = __expf(-1.702f * v);
  return v * __builtin_amdgcn_rcpf(1.f + s);
}
__device__ __forceinline__ void unpack8(uint4 v, float* o){
  o[0] = bf2f((u16)(v.x & 0xffffu)); o[1] = bf2f((u16)(v.x >> 16));
  o[2] = bf2f((u16)(v.y & 0xffffu)); o[3] = bf2f((u16)(v.y >> 16));
  o[4] = bf2f((u16)(v.z & 0xffffu)); o[5] = bf2f((u16)(v.z >> 16));
  o[6] = bf2f((u16)(v.w & 0xffffu)); o[7] = bf2f((u16)(v.w >> 16));
}

__device__ __forceinline__ void convw_body(const float* src, u16* dst,
                                           int dN, int dK, int sN, int sK, int idx){
  if (idx >= dN * dK) return;
  int n = idx / dK, k = idx % dK;
  dst[idx] = (n < sN && k < sK) ? f2bf(src[(size_t)n * sK + k]) : (u16)0;
}

// ---- mega-prep: embed (LDS-transposed, coalesced) | 4x weight conversions ----
// ranges: [0,4800) embed (block per (n,t)), [4800,6880) w_in, [6880,7712) w_out,
// [7712,10624) w1(1792 rows), [10624,13824) w2
#define PREP_GRID 13824
__global__ __launch_bounds__(256) void prep_kernel(const float* __restrict__ x,
                                                   const float* __restrict__ pe,
                                                   const float* __restrict__ w_in,
                                                   const float* __restrict__ w_out,
                                                   const float* __restrict__ w1,
                                                   const float* __restrict__ w2,
                                                   u16* __restrict__ xs,
                                                   u16* __restrict__ w_in_b,
                                                   u16* __restrict__ w_out_b,
                                                   u16* __restrict__ w1_b,
                                                   u16* __restrict__ w2_b){
  __shared__ float xv[400];
  int b = blockIdx.x;
  int tid = threadIdx.x;
  if (b < 4800){
    // block = (n,t): read x[n,:,t,:] in (c,v) order (25-float coalesced runs),
    // write xs row in d order (coalesced). d = v*16 + c.
    int t = b % T_, n = b / T_;
    for (int i = tid; i < 400; i += 256){
      int c = i / 25, v = i - c*25;
      xv[i] = x[(((size_t)(n*C_ + c))*T_ + t)*V_ + v];
    }
    __syncthreads();
    for (int d = tid; d < 400; d += 256){
      float val = xv[(d & 15)*25 + (d >> 4)] + pe[t*D_ + d];
      xs[(size_t)b * D_ + d] = f2bf(val);
    }
  } else if (b < 6880){
    convw_body(w_in,  w_in_b,  1280, KP_, 1200, D_,  (b - 4800) * 256 + tid);
  } else if (b < 7712){
    convw_body(w_out, w_out_b,  512, KP_,  400, D_,  (b - 6880) * 256 + tid);
  } else if (b < 10624){
    convw_body(w1,    w1_b,   1792, KP_, 1600, D_,  (b - 7712) * 256 + tid);
  } else {
    convw_body(w2,    w2_b,    512, SFF_, 400, FF_, (b - 10624) * 256 + tid);
  }
}

// ---- MFMA GEMM: 128x256 block tile, 8 waves (2M x 4N) of 64x64 each,
//      16 MFMA per wave-iter from 4+4 fragment reads (32.8 FLOP/LDS-byte),
//      3-deep LDS pipeline, cooperative global_load_lds (3 loads/thread:
//      1 A + 2 B halves), raw s_barrier + counted vmcnt(3) (never 0 mid-loop).
//      NOTE: no setprio -- R12 A/B showed it costs ~10% on this barrier-
//      lockstep structure (m190's null result confirmed here). ----
template<int ACT>
__global__ __launch_bounds__(512) void gemm_mfma(const u16* __restrict__ A, int lda,
                                                 const u16* __restrict__ B, int ldb,
                                                 const float* __restrict__ bias,
                                                 u16* __restrict__ C, int ldc,
                                                 int Nn, int KPd,
                                                 int gx, int gy){
  __shared__ u16 smem[36864];              // 72KB: A 3x8KB [0,12288), B 3x16KB [12288,36864)
  int id = blockIdx.x;
  int c  = id & 7, t = id >> 3;
  int bx = t % gx;
  int by = (t / gx) * 8 + c;               // XCD c owns M-tile residue class
  if (by >= gy) return;
  const int m0 = by * 128, n0 = bx * 256;

  const int tid  = threadIdx.x;
  const int lane = tid & 63;
  const int wv   = tid >> 6;               // 0..7
  const int quad = lane >> 4, l16 = lane & 15;
  const int wm   = wv & 1,   wn  = wv >> 1;   // wave grid: 2M x 4N, out 64x64/wave

  // staging map: A tile 128x32 (1 load/thread), B tile 256x32 (2 loads/thread)
  const int srow = tid >> 2;                          // 0..127
  const int sseg = (tid & 3) ^ ((tid >> 3) & 3);      // xor-swizzled k-segment
  const u16* Ag = A + (size_t)(m0 + srow) * lda + sseg*8;
  const u16* Bg = B + (size_t)(n0 + srow) * ldb + sseg*8;

  f32x4 acc[4][4] = {};
  const int sa = quad ^ ((l16 >> 1) & 3);             // read-side slot

  auto stage = [&](int buf, int kt){
    __builtin_amdgcn_global_load_lds(
        (const __attribute__((address_space(1))) void*)(Ag + kt),
        (__attribute__((address_space(3))) void*)(&smem[buf*4096 + wv*512]), 16, 0, 0);
    __builtin_amdgcn_global_load_lds(
        (const __attribute__((address_space(1))) void*)(Bg + kt),
        (__attribute__((address_space(3))) void*)(&smem[12288 + buf*8192 + wv*512]), 16, 0, 0);
    __builtin_amdgcn_global_load_lds(
        (const __attribute__((address_space(1))) void*)(Bg + kt + (size_t)128*ldb),
        (__attribute__((address_space(3))) void*)(&smem[12288 + buf*8192 + 4096 + wv*512]), 16, 0, 0);
  };

  const int nit = KPd >> 5;                // 13 or 50
  stage(0, 0);
  stage(1, 32);
  int nb = 2;
  for (int it = 0; it < nit; ++it){
    if (it < nit - 1) __builtin_amdgcn_s_waitcnt(WAIT_VM3);
    else              __builtin_amdgcn_s_waitcnt(WAIT_VM0);
    __builtin_amdgcn_s_barrier();
    if (it + 2 < nit){
      stage(nb, (it + 2) << 5);
      nb = (nb == 2) ? 0 : nb + 1;
    }
    const int buf = it % 3;
    const u16* Ar = &smem[buf*4096];
    const u16* Br = &smem[12288 + buf*8192];
    frag af[4], bfr[4];
    #pragma unroll
    for (int i = 0; i < 4; ++i)
      af[i]  = *(const frag*)(&Ar[(wm*64 + i*16 + l16)*32 + sa*8]);
    #pragma unroll
    for (int j = 0; j < 4; ++j)
      bfr[j] = *(const frag*)(&Br[(wn*64 + j*16 + l16)*32 + sa*8]);
    #pragma unroll
    for (int i = 0; i < 4; ++i)
      #pragma unroll
      for (int j = 0; j < 4; ++j)
        acc[i][j] = __builtin_amdgcn_mfma_f32_16x16x32_bf16(af[i], bfr[j], acc[i][j], 0, 0, 0);
  }

  __builtin_amdgcn_s_barrier();            // staging LDS now reusable

  u16* ep = &smem[wv * 4608];              // per-wave 64 rows x 72 u16 (8x4608=36864)
  #pragma unroll
  for (int j = 0; j < 4; ++j){
    int n = n0 + wn*64 + j*16 + l16;
    float bj = (n < Nn) ? bias[n] : 0.f;
    #pragma unroll
    for (int i = 0; i < 4; ++i){
      #pragma unroll
      for (int r = 0; r < 4; ++r){
        float v = acc[i][j][r] + bj;
        if (ACT) v = gelu_f(v);
        ep[(i*16 + quad*4 + r)*72 + j*16 + l16] = f2bf(v);
      }
    }
  }
  #pragma unroll
  for (int p = 0; p < 8; ++p){
    int row = p*8 + (lane >> 3);
    int seg = lane & 7;
    int nc  = n0 + wn*64 + seg*8;
    if (nc < Nn){                           // Nn multiple of 8 -> seg-exact
      uint4 v = *(const uint4*)(&ep[row*72 + seg*8]);
      *(uint4*)(C + (size_t)(m0 + wm*64 + row)*ldc + nc) = v;
    }
  }
}

// ---- MFMA GEMM, 128x128 variant (R2-verified): 8 waves (2M x 4N) of 64x32,
//      48KB LDS -> 3 blocks/CU. Used for the small-M qkv GEMM where the
//      128x256 variant only fills 190 blocks (37% of the machine): at gx=10
//      this gives 380 blocks at higher per-CU residency. ----
__global__ __launch_bounds__(512) void gemm_mfma128(const u16* __restrict__ A, int lda,
                                                    const u16* __restrict__ B, int ldb,
                                                    const float* __restrict__ bias,
                                                    u16* __restrict__ C, int ldc,
                                                    int Nn, int KPd,
                                                    int gx, int gy){
  __shared__ u16 smem[24576];              // 48KB: A bufs [0,12288), B bufs [12288,24576)
  int id = blockIdx.x;
  int c  = id & 7, t = id >> 3;
  int bx = t % gx;
  int by = (t / gx) * 8 + c;               // XCD c owns M-tile residue class
  if (by >= gy) return;
  const int m0 = by * 128, n0 = bx * 128;

  const int tid  = threadIdx.x;
  const int lane = tid & 63;
  const int wv   = tid >> 6;               // 0..7
  const int quad = lane >> 4, l16 = lane & 15;
  const int wm   = wv & 1,   wn  = wv >> 1;   // wave grid: 2M x 4N, out 64x32/wave

  // staging map: 512 threads cover a full 128x32 tile (1 load each per operand)
  const int srow = tid >> 2;                          // 0..127
  const int sseg = (tid & 3) ^ ((tid >> 3) & 3);      // xor-swizzled k-segment
  const u16* Ag = A + (size_t)(m0 + srow) * lda + sseg*8;
  const u16* Bg = B + (size_t)(n0 + srow) * ldb + sseg*8;

  f32x4 acc[4][2] = {};
  const int sa = quad ^ ((l16 >> 1) & 3);             // read-side slot

  auto stage = [&](int buf, int kt){
    __builtin_amdgcn_global_load_lds(
        (const __attribute__((address_space(1))) void*)(Ag + kt),
        (__attribute__((address_space(3))) void*)(&smem[buf*4096 + wv*512]), 16, 0, 0);
    __builtin_amdgcn_global_load_lds(
        (const __attribute__((address_space(1))) void*)(Bg + kt),
        (__attribute__((address_space(3))) void*)(&smem[12288 + buf*4096 + wv*512]), 16, 0, 0);
  };

  const int nit = KPd >> 5;                // 13
  stage(0, 0);
  stage(1, 32);
  int nb = 2;
  for (int it = 0; it < nit; ++it){
    if (it < nit - 1) __builtin_amdgcn_s_waitcnt(WAIT_VM2);
    else              __builtin_amdgcn_s_waitcnt(WAIT_VM0);
    __builtin_amdgcn_s_barrier();
    if (it + 2 < nit){
      stage(nb, (it + 2) << 5);
      nb = (nb == 2) ? 0 : nb + 1;
    }
    const int buf = it % 3;
    const u16* Ar = &smem[buf*4096];
    const u16* Br = &smem[12288 + buf*4096];
    frag af[4], bfr[2];
    #pragma unroll
    for (int i = 0; i < 4; ++i)
      af[i]  = *(const frag*)(&Ar[(wm*64 + i*16 + l16)*32 + sa*8]);
    #pragma unroll
    for (int j = 0; j < 2; ++j)
      bfr[j] = *(const frag*)(&Br[(wn*32 + j*16 + l16)*32 + sa*8]);
    #pragma unroll
    for (int i = 0; i < 4; ++i)
      #pragma unroll
      for (int j = 0; j < 2; ++j)
        acc[i][j] = __builtin_amdgcn_mfma_f32_16x16x32_bf16(af[i], bfr[j], acc[i][j], 0, 0, 0);
  }

  __builtin_amdgcn_s_barrier();            // staging LDS now reusable

  u16* ep = &smem[wv * 2560];              // per-wave 64 rows x 40 u16
  #pragma unroll
  for (int j = 0; j < 2; ++j){
    int n = n0 + wn*32 + j*16 + l16;
    float bj = (n < Nn) ? bias[n] : 0.f;
    #pragma unroll
    for (int i = 0; i < 4; ++i){
      #pragma unroll
      for (int r = 0; r < 4; ++r){
        float v = acc[i][j][r] + bj;
        ep[(i*16 + quad*4 + r)*40 + j*16 + l16] = f2bf(v);
      }
    }
  }
  #pragma unroll
  for (int p = 0; p < 4; ++p){
    int row = p*16 + (lane >> 2);
    int seg = lane & 3;
    int nc  = n0 + wn*32 + seg*8;
    if (nc < Nn){                           // Nn multiple of 8 -> seg-exact
      uint4 v = *(const uint4*)(&ep[row*40 + seg*8]);
      *(uint4*)(C + (size_t)(m0 + wm*64 + row)*ldc + nc) = v;
    }
  }
}

// ---- window-batched attention: 8 windows/block, bf16 LDS slab staging ----
#define WB_     8
#define ATT_NB  37                   // ceil(291/8)
#define ATT_GRID (N_ * ATT_NB)       // 592
__global__ __launch_bounds__(256) void attn_kernel(const u16* __restrict__ qkv,
                                                   u16* __restrict__ o,
                                                   int g0, int gend){
  __shared__ u16 kv[20480];          // 16 rows x 1200 u16 bf16
  __shared__ float att[WB_ * 2 * 81];  // [w][h][qi][ki]
  const int b  = blockIdx.x;
  const int n  = b / ATT_NB;
  const int w0 = (b - n * ATT_NB) * WB_;
  const int gbase = n * W_ + w0;
  if (gbase >= gend || gbase + WB_ <= g0) return;   // block outside chunk

  const int tid  = threadIdx.x;
  const int lane = tid & 63;
  const int wv   = tid >> 6;

  // stage 16 rows (38400B, rounded to 10 x 4KB rounds; over-read in-bounds
  // of the padded qkv buffer [4864][1200])
  const char* gsrc = (const char*)(qkv + (size_t)(n * T_ + w0) * SQKV_);
  #pragma unroll
  for (int j = 0; j < 10; ++j){
    __builtin_amdgcn_global_load_lds(
        (const __attribute__((address_space(1))) void*)(gsrc + j*4096 + wv*1024 + lane*16),
        (__attribute__((address_space(3))) void*)((char*)kv + j*4096 + wv*1024),
        16, 0, 0);
  }
  __builtin_amdgcn_s_waitcnt(WAIT_VM0);
  __syncthreads();

  // scores: 1296 tasks, each a 200-wide bf16 dot via 16B LDS reads
  for (int i = tid; i < WB_ * 162; i += 256){
    int w  = i / 162;
    int r  = i - w * 162;
    int h  = r / 81;
    int p  = r - h * 81;
    int qi = p / 9, ki = p - qi * 9;
    const u16* qp = kv + (w + qi) * 1200 + h * DH_;
    const u16* kp = kv + (w + ki) * 1200 + D_ + h * DH_;
    float s = 0.f;
    #pragma unroll 5
    for (int cch = 0; cch < 25; ++cch){
      float qa[8], kb[8];
      unpack8(*(const uint4*)(qp + cch*8), qa);
      unpack8(*(const uint4*)(kp + cch*8), kb);
      #pragma unroll
      for (int e = 0; e < 8; ++e) s += qa[e] * kb[e];
    }
    att[i] = s * 0.07071067811865475f;   // 1/sqrt(200)
  }
  __syncthreads();

  // softmax in place: one thread per (w,h,qi) row of 9
  if (tid < WB_ * 18){
    float* row = att + tid * 9;
    float mx = row[0];
    #pragma unroll
    for (int j = 1; j < 9; ++j) mx = fmaxf(mx, row[j]);
    float e[9]; float sum = 0.f;
    #pragma unroll
    for (int j = 0; j < 9; ++j){ e[j] = __expf(row[j] - mx); sum += e[j]; }
    float inv = 1.f / sum;
    #pragma unroll
    for (int j = 0; j < 9; ++j) row[j] = e[j] * inv;
  }
  __syncthreads();

  // PV: 7200 tasks, each 4 consecutive d (8B v reads), 9 MACs each
  for (int i = tid; i < WB_ * 900; i += 256){
    int w  = i / 900;
    int r  = i - w * 900;
    int l  = r / 100;
    int c4 = r - l * 100;                  // d0 = c4*4
    int h  = (c4 >= 50) ? 1 : 0;
    const float* ap = att + (w*2 + h)*81 + l*9;
    float o4[4] = {0.f, 0.f, 0.f, 0.f};
    #pragma unroll
    for (int ki = 0; ki < 9; ++ki){
      float a = ap[ki];
      uint2 vv = *(const uint2*)(kv + (w + ki)*1200 + 2*D_ + c4*4);
      o4[0] += a * bf2f((u16)(vv.x & 0xffffu));
      o4[1] += a * bf2f((u16)(vv.x >> 16));
      o4[2] += a * bf2f((u16)(vv.y & 0xffffu));
      o4[3] += a * bf2f((u16)(vv.y >> 16));
    }
    int g = gbase + w;
    if (w0 + w < W_ && g >= g0 && g < gend){
      u32 lo = (u32)f2bf(o4[0]) | ((u32)f2bf(o4[1]) << 16);
      u32 hi = (u32)f2bf(o4[2]) | ((u32)f2bf(o4[3]) << 16);
      *(uint2*)(o + ((size_t)(g - g0) * L_ + l) * SD_ + c4*4) = make_uint2(lo, hi);
    }
  }
}

// ---- LN1: h = LN(xs_window + y), wave-per-row ----
__global__ __launch_bounds__(256) void ln1_kernel(const u16* __restrict__ y,
                                                  const float* __restrict__ gam,
                                                  const float* __restrict__ bet,
                                                  u16* __restrict__ out,
                                                  const u16* __restrict__ xs,
                                                  int g0){
  const int wv = threadIdx.x >> 6, lane = threadIdx.x & 63;
  const int r = blockIdx.x * 4 + wv;
  const int g = g0 + r / L_, l = r % L_;
  const int n = g / W_, w = g % W_;
  const u16* arow = xs + ((size_t)(n*T_ + w + l)) * SD_;
  const u16* brow = y + (size_t)r * SD_;

  const bool act = lane < 50;
  float v[8];
  float s = 0.f, s2 = 0.f;
  if (act){
    float a8[8], b8[8];
    unpack8(*(const uint4*)(arow + lane*8), a8);
    unpack8(*(const uint4*)(brow + lane*8), b8);
    #pragma unroll
    for (int i = 0; i < 8; ++i){ v[i] = a8[i] + b8[i]; s += v[i]; s2 += v[i]*v[i]; }
  } else {
    #pragma unroll
    for (int i = 0; i < 8; ++i) v[i] = 0.f;
  }
  #pragma unroll
  for (int off = 32; off; off >>= 1){
    s  += __shfl_xor(s,  off);
    s2 += __shfl_xor(s2, off);
  }
  float mean = s * (1.f / D_);
  float rstd = rsqrtf(s2 * (1.f / D_) - mean*mean + 1e-5f);
  if (act){
    float4 ga = *(const float4*)(gam + lane*8);
    float4 gb = *(const float4*)(gam + lane*8 + 4);
    float4 ba = *(const float4*)(bet + lane*8);
    float4 bb = *(const float4*)(bet + lane*8 + 4);
    float gg[8] = {ga.x,ga.y,ga.z,ga.w, gb.x,gb.y,gb.z,gb.w};
    float bb8[8]= {ba.x,ba.y,ba.z,ba.w, bb.x,bb.y,bb.z,bb.w};
    u32 o4[4];
    #pragma unroll
    for (int i = 0; i < 4; ++i){
      u16 lo = f2bf((v[2*i]   - mean) * rstd * gg[2*i]   + bb8[2*i]);
      u16 hi = f2bf((v[2*i+1] - mean) * rstd * gg[2*i+1] + bb8[2*i+1]);
      o4[i] = (u32)lo | ((u32)hi << 16);
    }
    *(uint4*)(out + (size_t)r * SD_ + lane*8) = make_uint4(o4[0],o4[1],o4[2],o4[3]);
  }
}

// ---- fused LN2 + gather + transpose (nch==1 path; z eliminated) ----
// Each window-row (w,l) feeds exactly ONE output row t=(w>>1)+l, so the
// scatter has fan-out 1: one block per (n,t) loads its <=18 contributor
// (h,y) row-pairs (each consumed exactly once grid-wide), runs wave-per-row
// LN2 in-register, accumulates fp32 partials, writes transposed output.
// Blocks with t>153 have no contributors -> write zeros (matches reference).
__global__ __launch_bounds__(256) void ln2_gather(const u16* __restrict__ h,
                                                  const u16* __restrict__ y,
                                                  const float* __restrict__ gam,
                                                  const float* __restrict__ bet,
                                                  float* __restrict__ dout){
  __shared__ float buf[4][400];
  const int b = blockIdx.x;               // 0..4799
  const int t = b % T_;
  const int n = b / T_;
  const int wv = threadIdx.x >> 6, lane = threadIdx.x & 63;
  const bool act = lane < 50;

  float gg[8], bb8[8];
  if (act){
    float4 ga = *(const float4*)(gam + lane*8);
    float4 gb = *(const float4*)(gam + lane*8 + 4);
    float4 ba = *(const float4*)(bet + lane*8);
    float4 bb = *(const float4*)(bet + lane*8 + 4);
    gg[0]=ga.x; gg[1]=ga.y; gg[2]=ga.z; gg[3]=ga.w;
    gg[4]=gb.x; gg[5]=gb.y; gg[6]=gb.z; gg[7]=gb.w;
    bb8[0]=ba.x; bb8[1]=ba.y; bb8[2]=ba.z; bb8[3]=ba.w;
    bb8[4]=bb.x; bb8[5]=bb.y; bb8[6]=bb.z; bb8[7]=bb.w;
  }
  float racc[8] = {0.f,0.f,0.f,0.f,0.f,0.f,0.f,0.f};

  // contributor slots: idx -> (l = idx>>1, parity = idx&1), w = 2*(t-l)+parity
  for (int idx = wv; idx < 18; idx += 4){   // wave-uniform control flow
    int l  = idx >> 1;
    int dt = t - l;
    if (dt < 0 || dt > 145) continue;
    int w = dt * 2 + (idx & 1);
    if (w >= W_) continue;
    size_t r = ((size_t)(n * W_ + w)) * L_ + l;
    const u16* arow = h + r * SD_;
    const u16* brow = y + r * SD_;
    float v[8];
    float s = 0.f, s2 = 0.f;
    if (act){
      float a8[8], b8[8];
      unpack8(*(const uint4*)(arow + lane*8), a8);
      unpack8(*(const uint4*)(brow + lane*8), b8);
      #pragma unroll
      for (int i = 0; i < 8; ++i){ v[i] = a8[i] + b8[i]; s += v[i]; s2 += v[i]*v[i]; }
    } else {
      #pragma unroll
      for (int i = 0; i < 8; ++i) v[i] = 0.f;
    }
    #pragma unroll
    for (int off = 32; off; off >>= 1){
      s  += __shfl_xor(s,  off);
      s2 += __shfl_xor(s2, off);
    }
    float mean = s * (1.f / D_);
    float rstd = rsqrtf(s2 * (1.f / D_) - mean*mean + 1e-5f);
    if (act){
      #pragma unroll
      for (int i = 0; i < 8; ++i)
        racc[i] += (v[i] - mean) * rstd * gg[i] + bb8[i];
    }
  }
  if (act){
    #pragma unroll
    for (int i = 0; i < 8; ++i) buf[wv][lane*8 + i] = racc[i];
  }
  __syncthreads();
  for (int d = threadIdx.x; d < D_; d += 256){
    float s = buf[0][d] + buf[1][d] + buf[2][d] + buf[3][d];
    dout[(((size_t)(n*C_ + (d & 15)))*T_ + t)*V_ + (d >> 4)] = s;
  }
}

// ---- LN2 -> dense z rows in fp16 (nch>1 fallback path) ----
__global__ __launch_bounds__(256) void ln2z_kernel(const u16* __restrict__ h,
                                                   const u16* __restrict__ y,
                                                   const float* __restrict__ gam,
                                                   const float* __restrict__ bet,
                                                   u16* __restrict__ z,
                                                   int g0){
  const int wv = threadIdx.x >> 6, lane = threadIdx.x & 63;
  const int r = blockIdx.x * 4 + wv;
  const u16* arow = h + (size_t)r * SD_;
  const u16* brow = y + (size_t)r * SD_;

  const bool act = lane < 50;
  float v[8];
  float s = 0.f, s2 = 0.f;
  if (act){
    float a8[8], b8[8];
    unpack8(*(const uint4*)(arow + lane*8), a8);
    unpack8(*(const uint4*)(brow + lane*8), b8);
    #pragma unroll
    for (int i = 0; i < 8; ++i){ v[i] = a8[i] + b8[i]; s += v[i]; s2 += v[i]*v[i]; }
  } else {
    #pragma unroll
    for (int i = 0; i < 8; ++i) v[i] = 0.f;
  }
  #pragma unroll
  for (int off = 32; off; off >>= 1){
    s  += __shfl_xor(s,  off);
    s2 += __shfl_xor(s2, off);
  }
  float mean = s * (1.f / D_);
  float rstd = rsqrtf(s2 * (1.f / D_) - mean*mean + 1e-5f);
  if (act){
    float4 ga = *(const float4*)(gam + lane*8);
    float4 gb = *(const float4*)(gam + lane*8 + 4);
    float4 ba = *(const float4*)(bet + lane*8);
    float4 bb = *(const float4*)(bet + lane*8 + 4);
    float gg[8] = {ga.x,ga.y,ga.z,ga.w, gb.x,gb.y,gb.z,gb.w};
    float bb8[8]= {ba.x,ba.y,ba.z,ba.w, bb.x,bb.y,bb.z,bb.w};
    u32 o4[4];
    #pragma unroll
    for (int i = 0; i < 4; ++i){
      u16 lo = f2h((v[2*i]   - mean) * rstd * gg[2*i]   + bb8[2*i]);
      u16 hi = f2h((v[2*i+1] - mean) * rstd * gg[2*i+1] + bb8[2*i+1]);
      o4[i] = (u32)lo | ((u32)hi << 16);
    }
    *(uint4*)(z + ((size_t)(g0 * L_) + r) * SD_ + lane*8) = make_uint4(o4[0],o4[1],o4[2],o4[3]);
  }
}

// ---- gather + transpose from z (nch>1 fallback path) ----
__global__ __launch_bounds__(256) void gather_final(const u16* __restrict__ z,
                                                    float* __restrict__ dout){
  int idx = blockIdx.x * 256 + threadIdx.x;
  if (idx >= NT_ * D_) return;
  int d  = idx % D_;
  int nt = idx / D_;
  int t  = nt % T_;
  int n  = nt / T_;
  float s = 0.f;
  #pragma unroll
  for (int l = 0; l < L_; ++l){
    int dt = t - l;
    if (dt >= 0 && dt <= 145){            // w = 2*dt in [0, 291)
      int w = dt * 2;
      const u16* zp = z + ((size_t)((n*W_ + w)*L_ + l)) * SD_ + d;
      s += h2f(zp[0]);
      if (w + 1 < W_) s += h2f(zp[(size_t)L_ * SD_]);   // row (w+1, l)
    }
  }
  dout[(((size_t)(n*C_ + (d & 15)))*T_ + t)*V_ + (d >> 4)] = s;
}

extern "C" void kernel_launch(void* const* d_in, const int* in_sizes, int n_in,
                              void* d_out, int out_size, void* d_ws, size_t ws_size,
                              hipStream_t stream){
  (void)in_sizes; (void)n_in; (void)out_size;
  const float* x     = (const float*)d_in[0];
  const float* pe    = (const float*)d_in[1];
  const float* w_in  = (const float*)d_in[2];
  const float* b_in  = (const float*)d_in[3];
  const float* w_out = (const float*)d_in[4];
  const float* b_out = (const float*)d_in[5];
  const float* w1    = (const float*)d_in[6];
  const float* b1    = (const float*)d_in[7];
  const float* w2    = (const float*)d_in[8];
  const float* b2    = (const float*)d_in[9];
  const float* ln1g  = (const float*)d_in[10];
  const float* ln1b  = (const float*)d_in[11];
  const float* ln2g  = (const float*)d_in[12];
  const float* ln2b  = (const float*)d_in[13];

  // ws_size-adaptive chunk count (deterministic -> graph-safe).
  // Per-chunk footprint: y_c + h_c + ffc = RCP*4800 B (o_c aliases ffc head:
  // o_c is dead once FF1 writes ffc, and ffc is dead before the next chunk's
  // attn writes o_c).
  int nch = 3;
  {
    size_t need1 = (size_t)HEAD_END + (size_t)41984 * 4800;   // 1 chunk
    size_t need2 = (size_t)HEAD_END + (size_t)20992 * 4800;   // 2 chunks
    if (ws_size >= need1 + (1u<<20)) nch = 1;
    else if (ws_size >= need2 + (1u<<20)) nch = 2;
  }
  const int CW  = NW_ / nch;
  const int RC  = CW * L_;
  const int RCP = ((RC + 127) / 128) * 128;

  char* ws = (char*)d_ws;
  u16*   w_in_b  = (u16*)(ws + WIN_OFF);
  u16*   w_out_b = (u16*)(ws + WOUT_OFF);
  u16*   w1_b    = (u16*)(ws + W1_OFF);
  u16*   w2_b    = (u16*)(ws + W2_OFF);
  u16*   xs      = (u16*)(ws + XS_OFF);
  u16*   qkv     = (u16*)(ws + QKV_OFF);
  u16*   z       = (u16*)(ws + Z_OFF);
  u16*   y_c     = (u16*)(ws + HEAD_END);
  u16*   h_c     = y_c + (size_t)RCP * SD_;
  u16*   ffc     = h_c + (size_t)RCP * SD_;
  u16*   o_c     = ffc;                      // aliased (see lifetime note above)

  // one launch: embed + all 4 weight conversions
  prep_kernel<<<PREP_GRID, 256, 0, stream>>>(x, pe, w_in, w_out, w1, w2,
                                             xs, w_in_b, w_out_b, w1_b, w2_b);

  // qkv = xs @ w_in^T + b_in   [4800 x 1200] -- 128x128 variant: 380 blocks
  // at 3 blocks/CU vs 190 blocks at 2/CU for the 256-wide tile (fill-bound)
  {
    int gx = 10, gy = (NT_ + 127)/128, gy8 = (gy + 7) & ~7;
    gemm_mfma128<<<gx*gy8, 512, 0, stream>>>(
        xs, SD_, w_in_b, KP_, b_in, qkv, SQKV_, 1200, KP_, gx, gy);
  }

  const int gyc = RCP/128, gyc8 = (gyc + 7) & ~7;

  for (int g0 = 0; g0 < NW_; g0 += CW){
    attn_kernel<<<ATT_GRID, 256, 0, stream>>>(qkv, o_c, g0, g0 + CW);

    gemm_mfma<0><<<2*gyc8, 512, 0, stream>>>(
        o_c, SD_, w_out_b, KP_, b_out, y_c, SD_, D_, KP_, 2, gyc);

    ln1_kernel<<<RC/4, 256, 0, stream>>>(y_c, ln1g, ln1b, h_c, xs, g0);

    gemm_mfma<1><<<7*gyc8, 512, 0, stream>>>(
        h_c, SD_, w1_b, KP_, b1, ffc, SFF_, FF_, KP_, 7, gyc);

    gemm_mfma<0><<<2*gyc8, 512, 0, stream>>>(
        ffc, SFF_, w2_b, SFF_, b2, y_c, SD_, D_, SFF_, 2, gyc);

    if (nch > 1)
      ln2z_kernel<<<RC/4, 256, 0, stream>>>(h_c, y_c, ln2g, ln2b, z, g0);
  }

  if (nch == 1)
    ln2_gather<<<NT_, 256, 0, stream>>>(h_c, y_c, ln2g, ln2b, (float*)d_out);
  else
    gather_final<<<(NT_*D_ + 255)/256, 256, 0, stream>>>(z, (float*)d_out);
}